// Round 6
// baseline (218.708 us; speedup 1.0000x reference)
//
#include <hip/hip_runtime.h>

#define NUM_FEATURES 64
#define MAX_CAV 5
#define NX 704
#define NY 200
#define NUM_PIXELS (NY * NX)             // 140800
#define TOTAL_PIX (MAX_CAV * NUM_PIXELS) // 704000
#define N_PILLARS 60000
#define X4 (NX / 4)                      // 176
#define C_GROUPS 2                       // 64 channels / 32 per thread

typedef float f32x4 __attribute__((ext_vector_type(4)));
typedef int   i32x4 __attribute__((ext_vector_type(4)));

// ---------------------------------------------------------------------------
// Kernel 1: init the pixel->pillar map to -1 (d_ws is re-poisoned to 0xAA
// before every timed launch, so this must run every call). int4 stores.
// ---------------------------------------------------------------------------
__global__ void init_map_kernel(int* __restrict__ map) {
    int i = blockIdx.x * blockDim.x + threadIdx.x;       // index into int4 view
    if (i < TOTAL_PIX / 4) {
        i32x4 v = {-1, -1, -1, -1};
        reinterpret_cast<i32x4*>(map)[i] = v;
    }
}

// ---------------------------------------------------------------------------
// Kernel 2: scatter pillar ids into the map. coords layout: [N, 4] = (b,z,y,x).
// Flat indices are unique by construction (jax permutation), plain stores ok.
// ---------------------------------------------------------------------------
__global__ void scatter_ids_kernel(const int* __restrict__ coords,
                                   int* __restrict__ map) {
    int p = blockIdx.x * blockDim.x + threadIdx.x;
    if (p < N_PILLARS) {
        int b = coords[p * 4 + 0];
        int y = coords[p * 4 + 2];
        int x = coords[p * 4 + 3];
        map[b * NUM_PIXELS + y * NX + x] = p;
    }
}

// ---------------------------------------------------------------------------
// Kernel 3: output-driven gather. One thread owns 4 consecutive x positions
// x 32 channels. Per occupied pillar it reads a contiguous 128 B half-row
// (one L2 line, read by exactly one thread grid-wide) via nontemporal loads,
// register-transposes 4x4 blocks, and emits 32 nontemporal float4 stores
// (fully coalesced across the wave). Every output element written once ->
// no separate 180 MB zeroing pass.
// ---------------------------------------------------------------------------
__global__ void gather_out_kernel(const int* __restrict__ map,
                                  const float* __restrict__ feat,
                                  float* __restrict__ out) {
    const int total_t = MAX_CAV * C_GROUPS * NY * X4;    // 352000
    int t = blockIdx.x * blockDim.x + threadIdx.x;
    if (t >= total_t) return;

    int x4   = t % X4;
    int rest = t / X4;
    int y    = rest % NY;
    rest    /= NY;
    int g    = rest % C_GROUPS;          // channel group -> c0 = g*32
    int b    = rest / C_GROUPS;

    int pix4 = b * (NUM_PIXELS / 4) + y * X4 + x4;
    i32x4 m = reinterpret_cast<const i32x4*>(map)[pix4];
    const int c0 = g * 32;

    // base f32x4 index into out for (b, c0, y, x4); channel stride in f32x4s
    size_t obase = ((size_t)(b * NUM_FEATURES + c0) * NY + y) * X4 + x4;
    const size_t cstride = (size_t)NY * X4;              // 35200
    f32x4* __restrict__ o4 = reinterpret_cast<f32x4*>(out);

    const unsigned ux = (unsigned)m.x, uy = (unsigned)m.y;
    const unsigned uz = (unsigned)m.z, uw = (unsigned)m.w;

    #pragma unroll
    for (int q = 0; q < 8; ++q) {
        int c = c0 + q * 4;
        f32x4 f0 = {0.f, 0.f, 0.f, 0.f};
        f32x4 f1 = f0, f2 = f0, f3 = f0;
        if (ux < N_PILLARS)
            f0 = __builtin_nontemporal_load(
                reinterpret_cast<const f32x4*>(&feat[m.x * NUM_FEATURES + c]));
        if (uy < N_PILLARS)
            f1 = __builtin_nontemporal_load(
                reinterpret_cast<const f32x4*>(&feat[m.y * NUM_FEATURES + c]));
        if (uz < N_PILLARS)
            f2 = __builtin_nontemporal_load(
                reinterpret_cast<const f32x4*>(&feat[m.z * NUM_FEATURES + c]));
        if (uw < N_PILLARS)
            f3 = __builtin_nontemporal_load(
                reinterpret_cast<const f32x4*>(&feat[m.w * NUM_FEATURES + c]));

        // register transpose: channel-major stores over 4 consecutive x
        size_t ob = obase + (size_t)(q * 4) * cstride;
        f32x4 r0 = {f0.x, f1.x, f2.x, f3.x};
        f32x4 r1 = {f0.y, f1.y, f2.y, f3.y};
        f32x4 r2 = {f0.z, f1.z, f2.z, f3.z};
        f32x4 r3 = {f0.w, f1.w, f2.w, f3.w};
        __builtin_nontemporal_store(r0, &o4[ob]);
        __builtin_nontemporal_store(r1, &o4[ob + cstride]);
        __builtin_nontemporal_store(r2, &o4[ob + 2 * cstride]);
        __builtin_nontemporal_store(r3, &o4[ob + 3 * cstride]);
    }
}

extern "C" void kernel_launch(void* const* d_in, const int* in_sizes, int n_in,
                              void* d_out, int out_size, void* d_ws, size_t ws_size,
                              hipStream_t stream) {
    const int*   coords = reinterpret_cast<const int*>(d_in[0]);     // [N,4] int32
    const float* feat   = reinterpret_cast<const float*>(d_in[1]);   // [N,64] f32
    float*       out    = reinterpret_cast<float*>(d_out);           // [5,64,200,704]
    int*         map    = reinterpret_cast<int*>(d_ws);              // 704000 ints

    // 1) map <- -1
    {
        int n = TOTAL_PIX / 4;                 // 176000
        int blocks = (n + 255) / 256;
        init_map_kernel<<<blocks, 256, 0, stream>>>(map);
    }
    // 2) map[pixel] <- pillar id
    {
        int blocks = (N_PILLARS + 255) / 256;
        scatter_ids_kernel<<<blocks, 256, 0, stream>>>(coords, map);
    }
    // 3) coalesced gather into output
    {
        int n = MAX_CAV * C_GROUPS * NY * X4;  // 352000
        int blocks = (n + 255) / 256;          // 1375
        gather_out_kernel<<<blocks, 256, 0, stream>>>(map, feat, out);
    }
}

// Round 7
// 202.556 us; speedup vs baseline: 1.0797x; 1.0797x over previous
//
#include <hip/hip_runtime.h>

#define NUM_FEATURES 64
#define MAX_CAV 5
#define NX 704
#define NY 200
#define NUM_PIXELS (NY * NX)             // 140800
#define TOTAL_PIX (MAX_CAV * NUM_PIXELS) // 704000
#define N_PILLARS 60000
#define X4 (NX / 4)                      // 176
#define C_GROUPS 2                       // 64 channels / 32 per thread

typedef float f32x4 __attribute__((ext_vector_type(4)));
typedef int   i32x4 __attribute__((ext_vector_type(4)));

// ---------------------------------------------------------------------------
// Kernel 1: init the pixel->pillar map to -1 (d_ws is re-poisoned to 0xAA
// before every timed launch, so this must run every call). int4 stores.
// ---------------------------------------------------------------------------
__global__ void init_map_kernel(int* __restrict__ map) {
    int i = blockIdx.x * blockDim.x + threadIdx.x;       // index into int4 view
    if (i < TOTAL_PIX / 4) {
        i32x4 v = {-1, -1, -1, -1};
        reinterpret_cast<i32x4*>(map)[i] = v;
    }
}

// ---------------------------------------------------------------------------
// Kernel 2: scatter pillar ids into the map. coords layout: [N, 4] = (b,z,y,x).
// Flat indices are unique by construction (jax permutation), plain stores ok.
// ---------------------------------------------------------------------------
__global__ void scatter_ids_kernel(const int* __restrict__ coords,
                                   int* __restrict__ map) {
    int p = blockIdx.x * blockDim.x + threadIdx.x;
    if (p < N_PILLARS) {
        int b = coords[p * 4 + 0];
        int y = coords[p * 4 + 2];
        int x = coords[p * 4 + 3];
        map[b * NUM_PIXELS + y * NX + x] = p;
    }
}

// ---------------------------------------------------------------------------
// Kernel 3: output-driven gather. One thread owns 4 consecutive x positions
// x 32 channels. Per occupied pillar it reads a contiguous 128 B half-row
// with NORMAL cached loads (first 16 B load misses, L1 serves the other 7 —
// each 128 B feat line is owned by exactly one thread grid-wide), register-
// transposes 4x4 blocks, and emits 32 NONTEMPORAL float4 stores (streaming
// 180 MB without evicting map/feat from L2). Every output element is written
// exactly once -> no separate 180 MB zeroing pass.
// ---------------------------------------------------------------------------
__global__ void gather_out_kernel(const int* __restrict__ map,
                                  const float* __restrict__ feat,
                                  float* __restrict__ out) {
    const int total_t = MAX_CAV * C_GROUPS * NY * X4;    // 352000
    int t = blockIdx.x * blockDim.x + threadIdx.x;
    if (t >= total_t) return;

    int x4   = t % X4;
    int rest = t / X4;
    int y    = rest % NY;
    rest    /= NY;
    int g    = rest % C_GROUPS;          // channel group -> c0 = g*32
    int b    = rest / C_GROUPS;

    int pix4 = b * (NUM_PIXELS / 4) + y * X4 + x4;
    i32x4 m = reinterpret_cast<const i32x4*>(map)[pix4];
    const int c0 = g * 32;

    // base f32x4 index into out for (b, c0, y, x4); channel stride in f32x4s
    size_t obase = ((size_t)(b * NUM_FEATURES + c0) * NY + y) * X4 + x4;
    const size_t cstride = (size_t)NY * X4;              // 35200
    f32x4* __restrict__ o4 = reinterpret_cast<f32x4*>(out);

    const unsigned ux = (unsigned)m.x, uy = (unsigned)m.y;
    const unsigned uz = (unsigned)m.z, uw = (unsigned)m.w;

    #pragma unroll
    for (int q = 0; q < 8; ++q) {
        int c = c0 + q * 4;
        f32x4 f0 = {0.f, 0.f, 0.f, 0.f};
        f32x4 f1 = f0, f2 = f0, f3 = f0;
        if (ux < N_PILLARS)
            f0 = *reinterpret_cast<const f32x4*>(&feat[m.x * NUM_FEATURES + c]);
        if (uy < N_PILLARS)
            f1 = *reinterpret_cast<const f32x4*>(&feat[m.y * NUM_FEATURES + c]);
        if (uz < N_PILLARS)
            f2 = *reinterpret_cast<const f32x4*>(&feat[m.z * NUM_FEATURES + c]);
        if (uw < N_PILLARS)
            f3 = *reinterpret_cast<const f32x4*>(&feat[m.w * NUM_FEATURES + c]);

        // register transpose: channel-major stores over 4 consecutive x
        size_t ob = obase + (size_t)(q * 4) * cstride;
        f32x4 r0 = {f0.x, f1.x, f2.x, f3.x};
        f32x4 r1 = {f0.y, f1.y, f2.y, f3.y};
        f32x4 r2 = {f0.z, f1.z, f2.z, f3.z};
        f32x4 r3 = {f0.w, f1.w, f2.w, f3.w};
        __builtin_nontemporal_store(r0, &o4[ob]);
        __builtin_nontemporal_store(r1, &o4[ob + cstride]);
        __builtin_nontemporal_store(r2, &o4[ob + 2 * cstride]);
        __builtin_nontemporal_store(r3, &o4[ob + 3 * cstride]);
    }
}

extern "C" void kernel_launch(void* const* d_in, const int* in_sizes, int n_in,
                              void* d_out, int out_size, void* d_ws, size_t ws_size,
                              hipStream_t stream) {
    const int*   coords = reinterpret_cast<const int*>(d_in[0]);     // [N,4] int32
    const float* feat   = reinterpret_cast<const float*>(d_in[1]);   // [N,64] f32
    float*       out    = reinterpret_cast<float*>(d_out);           // [5,64,200,704]
    int*         map    = reinterpret_cast<int*>(d_ws);              // 704000 ints

    // 1) map <- -1
    {
        int n = TOTAL_PIX / 4;                 // 176000
        int blocks = (n + 255) / 256;
        init_map_kernel<<<blocks, 256, 0, stream>>>(map);
    }
    // 2) map[pixel] <- pillar id
    {
        int blocks = (N_PILLARS + 255) / 256;
        scatter_ids_kernel<<<blocks, 256, 0, stream>>>(coords, map);
    }
    // 3) coalesced gather into output
    {
        int n = MAX_CAV * C_GROUPS * NY * X4;  // 352000
        int blocks = (n + 255) / 256;          // 1375
        gather_out_kernel<<<blocks, 256, 0, stream>>>(map, feat, out);
    }
}